// Round 13
// baseline (454.089 us; speedup 1.0000x reference)
//
#include <hip/hip_runtime.h>

typedef unsigned short u16;
typedef unsigned int u32;
typedef unsigned long long u64;

#define B_TOTAL 65536
#define H 512
#define D 64
#define BM 32

typedef __bf16 bf16x8 __attribute__((ext_vector_type(8)));
typedef float f32x4 __attribute__((ext_vector_type(4)));

__device__ __forceinline__ u32 f2b(float f) {  // fp32 -> bf16 bits, RNE (sw)
  u32 u = __builtin_bit_cast(u32, f);
  return (u + 0x7fffu + ((u >> 16) & 1u)) >> 16;
}
__device__ __forceinline__ u16 f2bc(float f) { // fp32 -> bf16 bits via HW cvt
  return __builtin_bit_cast(u16, (__bf16)f);   // RNE; compiler pairs into
}                                              // v_cvt_pk_bf16_f32
__device__ __forceinline__ float b2f(u32 bits) {
  return __builtin_bit_cast(float, bits << 16);
}

// ---- workspace layout (bf16 element offsets) ----
// Weight regions are FRAGMENT-PACKED: for logical B-matrix M[NN][KK],
// packed[( (n>>4)*(KK/32) + (k>>5) )*512 + lane*8 + j] = M[n][k],
// n = ntile*16 + (lane&15), k = kstep*32 + (lane>>4)*8 + j.
#define OFF_Wz0b 0          /* [N=512][K=64]  fwd L0 */
#define OFF_Wx0b 32768
#define OFF_Wx1b 65536
#define OFF_Wx2b 98304
#define OFF_Wz1b 131072     /* [N=512][K=512] fwd */
#define OFF_Wz2b 393216
#define OFF_Wz3b 655360
#define OFF_Wz1t 917504     /* [N=512][K=512] transposed, bwd */
#define OFF_Wz2t 1179648
#define OFF_Wz3t 1441792
#define OFF_Wz0t 1703936    /* [N=64][K=512] transposed grad weights */
#define OFF_Wx0t 1736704
#define OFF_Wx1t 1769472
#define OFF_Wx2t 1802240
#define OFF_WEND 1835008
// Slabs deleted in R9 (sigmoids live in registers); workspace is weights only.
#define WS_ELEMS OFF_WEND

// ---- weight prep: fp32 -> bf16, fragment-packed (+ transposed variants) ----
__global__ __launch_bounds__(256) void prep_kernel(
    const float* __restrict__ Wz0, const float* __restrict__ Wz1,
    const float* __restrict__ Wz2, const float* __restrict__ Wz3,
    const float* __restrict__ Wx0, const float* __restrict__ Wx1,
    const float* __restrict__ Wx2, u16* __restrict__ wsb) {
  int i = blockIdx.x * 256 + threadIdx.x;   // grid exactly covers OFF_WEND
  const float* src;
  int NN, KK, trans, p;
  if (i < 131072) {                          // x-path fwd: [512][64] direct
    int r = i >> 15; p = i & 32767;
    src = (r == 0) ? Wz0 : (r == 1) ? Wx0 : (r == 2) ? Wx1 : Wx2;
    NN = 512; KK = 64; trans = 0;
  } else if (i < 917504) {                   // H fwd: [512][512] direct
    int j = i - 131072; int r = j >> 18; p = j & 262143;
    src = (r == 0) ? Wz1 : (r == 1) ? Wz2 : Wz3;
    NN = 512; KK = 512; trans = 0;
  } else if (i < 1703936) {                  // H bwd: transposed
    int j = i - 917504; int r = j >> 18; p = j & 262143;
    src = (r == 0) ? Wz1 : (r == 1) ? Wz2 : Wz3;
    NN = 512; KK = 512; trans = 1;
  } else {                                   // grad weights: [64][512] = W^T
    int j = i - 1703936; int r = j >> 15; p = j & 32767;
    src = (r == 0) ? Wz0 : (r == 1) ? Wx0 : (r == 2) ? Wx1 : Wx2;
    NN = 64; KK = 512; trans = 1;
  }
  int jj = p & 7, lane = (p >> 3) & 63, blk = p >> 9;
  int kt_sh = (KK == 64) ? 1 : 4;            // log2(KK/32)
  int ntile = blk >> kt_sh;
  int kstep = blk & ((1 << kt_sh) - 1);
  int n = ntile * 16 + (lane & 15);
  int k = kstep * 32 + ((lane >> 4) << 3) + jj;
  float v = trans ? src[k * NN + n] : src[n * KK + k];
  wsb[i] = (u16)f2b(v);
}

__global__ __launch_bounds__(256) void fill_sentinel(float* out, int n) {
  int i = blockIdx.x * 256 + threadIdx.x;
  if (i < n) out[i] = 12345.0f;   // unmistakable "workspace too small" marker
}

// ---- fully-fused ICNN fwd+bwd (single GEMM kernel) ----
// ROUND-13 = ROUND-12 (346us) at HALF BLOCK SIZE for inter-block overlap.
// R12 analysis: MFMA pipe busy 110us (= exactly the work's 118us floor at
// the per-SIMD 16x16 rate), VALU 152us, ~24% stall. The layer barrier
// forces all waves of a block into lockstep VALU-burst (epilogue) then
// MFMA-burst (fwdH) phases -- intra-block overlap is structurally capped
// (fwdH A-frags span all K=512 cols, so the barrier is mandatory).
// FIX: BM=32, 512 thr, 8 waves, LDS 68.6KB -> TWO INDEPENDENT BLOCKS/CU.
// Same 16 waves/CU, but one block's epilogue VALU now overlaps the OTHER
// block's fwdH MFMA. Per-block structure identical to R12 (col-split
// wave ownership [w*64,+64), acc[2][4], K-major ping-pong zbuf, register
// sigmoids, LDS-only barriers, setprio, minigrad chain-split). B-prefetch
// back to depth-1: the 2-block TLP is the latency hider, and depth-2's
// 3x b[4] levels (48 regs) would not fit the 128 cap.
// Cost accepted: 2x weight L2 traffic (6.3GB, L2-resident), +15% fwdH
// addressing VALU per unit work.
__global__ __launch_bounds__(512, 4) void icnn_kernel(
    const float* __restrict__ state,
    const float* __restrict__ bz0, const float* __restrict__ bx0,
    const float* __restrict__ bx1, const float* __restrict__ bx2,
    const float* __restrict__ WzL, const float* __restrict__ WxL,
    u16* __restrict__ wsw, float* __restrict__ out) {
  __shared__ u16 zbA[BM * H];       // K-major activations, ping  (32 KB)
  __shared__ u16 zbB[BM * H];       // K-major activations, pong  (32 KB)
  __shared__ u16 xbuf[BM * 72];     // padded x staging, 4.5 KB

  const int tid = threadIdx.x;
  const int w = tid >> 6;           // 0..7
  const int lane = tid & 63;
  const int l15 = lane & 15;
  const int q = lane >> 4;
  const int blk = blockIdx.x;

  const u16* Wz0b = wsw + OFF_Wz0b;
  const u16* Wx0b = wsw + OFF_Wx0b;
  const u16* Wx1b = wsw + OFF_Wx1b;
  const u16* Wx2b = wsw + OFF_Wx2b;
  const u16* Wz1b = wsw + OFF_Wz1b;
  const u16* Wz2b = wsw + OFF_Wz2b;
  const u16* Wz3b = wsw + OFF_Wz3b;
  const u16* Wz1t = wsw + OFF_Wz1t;
  const u16* Wz2t = wsw + OFF_Wz2t;
  const u16* Wz3t = wsw + OFF_Wz3t;
  const u16* Wz0t = wsw + OFF_Wz0t;
  const u16* Wx0t = wsw + OFF_Wx0t;
  const u16* Wx1t = wsw + OFF_Wx1t;
  const u16* Wx2t = wsw + OFF_Wx2t;

  // LDS-only barrier: orders zbuf ds ops across waves; global loads/stores
  // stay in flight across it (no vmcnt drain).
  auto lbar = [&]() {
    asm volatile("s_waitcnt lgkmcnt(0)" ::: "memory");
    __builtin_amdgcn_s_barrier();
    asm volatile("" ::: "memory");
  };

  // ---- stage x = state-1 into xbuf (bf16, padded row-major) ----
  {
    int r = tid >> 4, c0 = (tid & 15) << 2;  // 32 rows x 16 chunks of 4 floats
    const float* p = state + (blk * BM + r) * D + c0;
    f32x4 v = __builtin_nontemporal_load((const f32x4*)p);
    u32* dst = (u32*)&xbuf[r * 72 + c0];
    dst[0] = (u32)f2bc(v[0] - 1.0f) | ((u32)f2bc(v[1] - 1.0f) << 16);
    dst[1] = (u32)f2bc(v[2] - 1.0f) | ((u32)f2bc(v[3] - 1.0f) << 16);
  }

  f32x4 acc[2][4];                  // 32 acc regs: 32 rows x 64 cols / wave
  const f32x4 Z = {0.f, 0.f, 0.f, 0.f};
  f32x4 pk = Z;                     // grad park: wave's single 16x16 out tile
  u64 sg0[8], sg1[8], sg2[8];       // register-resident sigmoids, 48 VGPRs

  // K-major zbuf reads: A-frag (row tile mt in [0,2), K-step st): lane
  // (q,l15) needs z[mt*16+l15][st*32+q*8..+8] -> offset
  // (st*2+mt)*512 + q*128 + l15*8. 64 lanes cover one contiguous 1KB
  // span: zero bank conflicts.
  auto ldA = [&](const u16* zb, int mt, int step) -> bf16x8 {
    return *(const bf16x8*)(&zb[(step * 2 + mt) * 512 + q * 128 + l15 * 8]);
  };
  auto ldX = [&](int mt, int ks) -> bf16x8 {       // x A-frag from padded xbuf
    return *(const bf16x8*)(&xbuf[(mt * 16 + l15) * 72 + ks * 32 + q * 8]);
  };
  auto wrZ = [&](u16* zb, int row, int n, u16 bits) {  // K-major scatter write
    zb[((n >> 5) * 2 + (row >> 4)) * 512 + ((n >> 3) & 3) * 128 +
       (row & 15) * 8 + (n & 7)] = bits;
  };
  auto zeroAcc = [&]() {
#pragma unroll
    for (int mt = 0; mt < 2; ++mt)
#pragma unroll
      for (int nt = 0; nt < 4; ++nt) acc[mt][nt] = Z;
  };

  // acc = x @ Wx^T (K=64), zero-start. Wx streams global->VGPR.
  auto fwdX = [&](const u16* Wxp) {
    const u16* xb = Wxp + lane * 8;
#pragma unroll
    for (int ks = 0; ks < 2; ++ks) {
      bf16x8 b4[4];
#pragma unroll
      for (int nt = 0; nt < 4; ++nt)
        b4[nt] = *(const bf16x8*)(xb + ((w * 4 + nt) * 2 + ks) * 512);
#pragma unroll
      for (int mt = 0; mt < 2; ++mt) {
        bf16x8 ax = ldX(mt, ks);
#pragma unroll
        for (int nt = 0; nt < 4; ++nt) {
          f32x4 c = (ks == 0) ? Z : acc[mt][nt];
          acc[mt][nt] = __builtin_amdgcn_mfma_f32_16x16x32_bf16(ax, b4[nt], c, 0, 0, 0);
        }
      }
    }
  };

  // acc += zb @ W^T (K=512), ALWAYS accumulating (callers zeroAcc first
  // if needed). B streams global->VGPR with depth-1 rotation (2 live
  // levels of b[4] = 32 regs); the co-resident second block provides the
  // latency-hiding TLP. unroll 2 renames the rotation away.
  auto fwdH = [&](const u16* Wp, const u16* zb) {
    const u16* gb = Wp + (w * 4 * 16) * 512 + lane * 8;
    bf16x8 bc0 = *(const bf16x8*)(gb);
    bf16x8 bc1 = *(const bf16x8*)(gb + 16 * 512);
    bf16x8 bc2 = *(const bf16x8*)(gb + 32 * 512);
    bf16x8 bc3 = *(const bf16x8*)(gb + 48 * 512);
#pragma unroll 2
    for (int st = 0; st < 16; ++st) {
      int stn = (st < 15) ? st + 1 : st;   // prefetch st+1 (clamped re-read)
      bf16x8 bn0 = *(const bf16x8*)(gb + stn * 512);
      bf16x8 bn1 = *(const bf16x8*)(gb + (16 + stn) * 512);
      bf16x8 bn2 = *(const bf16x8*)(gb + (32 + stn) * 512);
      bf16x8 bn3 = *(const bf16x8*)(gb + (48 + stn) * 512);
      bf16x8 a[2];
#pragma unroll
      for (int mt = 0; mt < 2; ++mt) a[mt] = ldA(zb, mt, st);
      __builtin_amdgcn_s_setprio(1);
#pragma unroll
      for (int mt = 0; mt < 2; ++mt)
        acc[mt][0] = __builtin_amdgcn_mfma_f32_16x16x32_bf16(a[mt], bc0, acc[mt][0], 0, 0, 0);
#pragma unroll
      for (int mt = 0; mt < 2; ++mt)
        acc[mt][1] = __builtin_amdgcn_mfma_f32_16x16x32_bf16(a[mt], bc1, acc[mt][1], 0, 0, 0);
#pragma unroll
      for (int mt = 0; mt < 2; ++mt)
        acc[mt][2] = __builtin_amdgcn_mfma_f32_16x16x32_bf16(a[mt], bc2, acc[mt][2], 0, 0, 0);
#pragma unroll
      for (int mt = 0; mt < 2; ++mt)
        acc[mt][3] = __builtin_amdgcn_mfma_f32_16x16x32_bf16(a[mt], bc3, acc[mt][3], 0, 0, 0);
      __builtin_amdgcn_s_setprio(0);
      bc0 = bn0; bc1 = bn1; bc2 = bn2; bc3 = bn3;
    }
  };

  // forward epilogue: a+=bias; z=softplus -> zb; s=sigmoid -> sg (registers)
  auto fwd_epi = [&](const float* biasp, u64 (&sg)[8], u16* zb) {
    float bias[4];
#pragma unroll
    for (int nt = 0; nt < 4; ++nt) bias[nt] = biasp[(w * 4 + nt) * 16 + l15];
#pragma unroll
    for (int mt = 0; mt < 2; ++mt)
#pragma unroll
      for (int nt = 0; nt < 4; ++nt) {
        int n = (w * 4 + nt) * 16 + l15;
        f32x4 A = acc[mt][nt];
        u64 pack = 0;
#pragma unroll
        for (int r = 0; r < 4; ++r) {
          float a = A[r] + bias[nt];
          float t = __expf(-a);
          float u = 1.0f + t;
          float s = __builtin_amdgcn_rcpf(u);     // sigmoid(a)
          float z = a + __logf(u);                // softplus(a)
          pack |= (u64)f2bc(s) << (16 * r);
          wrZ(zb, mt * 16 + q * 4 + r, n, f2bc(z));
        }
        sg[mt * 4 + nt] = pack;                   // static index (full unroll)
      }
  };
  auto d3_epi = [&](const float* biasp, u16* zb) {  // d3 = WzL*sigmoid(a3)
    float bias[4], wl[4];
#pragma unroll
    for (int nt = 0; nt < 4; ++nt) {
      bias[nt] = biasp[(w * 4 + nt) * 16 + l15];
      wl[nt] = WzL[(w * 4 + nt) * 16 + l15];
    }
#pragma unroll
    for (int mt = 0; mt < 2; ++mt)
#pragma unroll
      for (int nt = 0; nt < 4; ++nt) {
        int n = (w * 4 + nt) * 16 + l15;
        f32x4 A = acc[mt][nt];
#pragma unroll
        for (int r = 0; r < 4; ++r) {
          float a = A[r] + bias[nt];
          float t = __expf(-a);
          float s = __builtin_amdgcn_rcpf(1.0f + t);
          wrZ(zb, mt * 16 + q * 4 + r, n, f2bc(wl[nt] * s));
        }
      }
  };
  // d = g * s -> zb (s from registers; same thread produced both)
  auto bwd_epi = [&](const u64 (&sg)[8], u16* zb) {
#pragma unroll
    for (int mt = 0; mt < 2; ++mt)
#pragma unroll
      for (int nt = 0; nt < 4; ++nt) {
        int n = (w * 4 + nt) * 16 + l15;
        f32x4 A = acc[mt][nt];
        u64 v = sg[mt * 4 + nt];                  // static index
#pragma unroll
        for (int r = 0; r < 4; ++r) {
          float s = b2f((u32)(v >> (16 * r)) & 0xffffu);
          wrZ(zb, mt * 16 + q * 4 + r, n, f2bc(A[r] * s));
        }
      }
  };

  // grad mini-phase: pk += zb(d) @ Wg (main acc is DEAD here).
  // 8 waves <-> 8 out tiles of the [32,64] grad: wave w owns tile
  // (rt=w&1, ct=w>>1). Chain split even/odd: two independent 8-deep
  // MFMA chains instead of one 16-deep dependent chain.
  auto minigrad = [&](const u16* Wg, const u16* zb, bool init) {
    int rt = w & 1, ct = w >> 1;
    const u16* gb = Wg + lane * 8;
    f32x4 ta = init ? Z : pk, tb = Z;
#pragma unroll 2
    for (int st = 0; st < 16; st += 2) {
      bf16x8 a0 = ldA(zb, rt, st);
      bf16x8 g0 = *(const bf16x8*)(gb + (ct * 16 + st) * 512);
      bf16x8 a1 = ldA(zb, rt, st + 1);
      bf16x8 g1 = *(const bf16x8*)(gb + (ct * 16 + st + 1) * 512);
      __builtin_amdgcn_s_setprio(1);
      ta = __builtin_amdgcn_mfma_f32_16x16x32_bf16(a0, g0, ta, 0, 0, 0);
      tb = __builtin_amdgcn_mfma_f32_16x16x32_bf16(a1, g1, tb, 0, 0, 0);
      __builtin_amdgcn_s_setprio(0);
    }
    pk = ta + tb;
  };

  // ---------------- forward ----------------
  lbar();                                   // xbuf ready
  fwdX(Wz0b);                               // a0 = x@Wz0^T
  fwd_epi(bz0, sg0, zbA);                   // z0 -> zbA, s0 -> regs
  lbar();                                   // P0
  fwdX(Wx0b); fwdH(Wz1b, zbA);              // a1 = x@Wx0^T + z0@Wz1^T
  fwd_epi(bx0, sg1, zbB);                   // z1 -> zbB (zbA still readable)
  lbar();                                   // P1
  fwdX(Wx1b); fwdH(Wz2b, zbB);              // a2
  fwd_epi(bx1, sg2, zbA);                   // z2 -> zbA
  lbar();                                   // P2
  fwdX(Wx2b); fwdH(Wz3b, zbA);              // a3
  d3_epi(bx2, zbB);                         // d3 -> zbB
  lbar();                                   // P3
  // ---------------- backward ----------------
  minigrad(Wx2t, zbB, true);                // pk  = d3@Wx2t
  zeroAcc(); fwdH(Wz3t, zbB);               // acc = d3@Wz3
  bwd_epi(sg2, zbA);                        // d2 -> zbA
  lbar();                                   // P4
  minigrad(Wx1t, zbA, false);               // pk += d2@Wx1t
  zeroAcc(); fwdH(Wz2t, zbA);               // acc = d2@Wz2
  bwd_epi(sg1, zbB);                        // d1 -> zbB
  lbar();                                   // P5
  minigrad(Wx0t, zbB, false);               // pk += d1@Wx0t
  zeroAcc(); fwdH(Wz1t, zbB);               // acc = d1@Wz1
  bwd_epi(sg0, zbA);                        // d0 -> zbA
  lbar();                                   // P6
  // ---- final: out = d0@Wz0t + pk + WxL ----
  minigrad(Wz0t, zbA, false);               // pk += d0@Wz0t
  {
    int rt = w & 1, ct = w >> 1;
    float wx = WxL[ct * 16 + l15];
#pragma unroll
    for (int r = 0; r < 4; ++r) {
      int row = blk * BM + rt * 16 + q * 4 + r;
      out[row * D + ct * 16 + l15] = pk[r] + wx;
    }
  }
}

extern "C" void kernel_launch(void* const* d_in, const int* in_sizes, int n_in,
                              void* d_out, int out_size, void* d_ws, size_t ws_size,
                              hipStream_t stream) {
  const float* state = (const float*)d_in[0];
  const float* Wz0 = (const float*)d_in[1];
  const float* bz0 = (const float*)d_in[2];
  const float* Wz1 = (const float*)d_in[3];
  const float* Wz2 = (const float*)d_in[4];
  const float* Wz3 = (const float*)d_in[5];
  const float* WzL = (const float*)d_in[6];
  const float* Wx0 = (const float*)d_in[7];
  const float* bx0 = (const float*)d_in[8];
  const float* Wx1 = (const float*)d_in[9];
  const float* bx1 = (const float*)d_in[10];
  const float* Wx2 = (const float*)d_in[11];
  const float* bx2 = (const float*)d_in[12];
  const float* WxL = (const float*)d_in[13];

  if (ws_size < (size_t)WS_ELEMS * 2) {
    fill_sentinel<<<(out_size + 255) / 256, 256, 0, stream>>>((float*)d_out, out_size);
    return;
  }
  u16* wsw = (u16*)d_ws;
  prep_kernel<<<OFF_WEND / 256, 256, 0, stream>>>(Wz0, Wz1, Wz2, Wz3, Wx0, Wx1, Wx2, wsw);
  icnn_kernel<<<B_TOTAL / BM, 512, 0, stream>>>(state, bz0, bx0, bx1, bx2, WzL, WxL,
                                                wsw, (float*)d_out);
}

// Round 14
// 413.969 us; speedup vs baseline: 1.0969x; 1.0969x over previous
//
#include <hip/hip_runtime.h>

typedef unsigned short u16;
typedef unsigned int u32;
typedef unsigned long long u64;

#define B_TOTAL 65536
#define H 512
#define D 64
#define BM 64
#define CH 520   /* zbuf chunk stride in u16 (512 data + 8 pad: de-conflicts writes) */

typedef __bf16 bf16x8 __attribute__((ext_vector_type(8)));
typedef float f32x4 __attribute__((ext_vector_type(4)));
typedef float f32x16 __attribute__((ext_vector_type(16)));

__device__ __forceinline__ u32 f2b(float f) {  // fp32 -> bf16 bits, RNE (sw)
  u32 u = __builtin_bit_cast(u32, f);
  return (u + 0x7fffu + ((u >> 16) & 1u)) >> 16;
}
__device__ __forceinline__ u16 f2bc(float f) { // fp32 -> bf16 bits via HW cvt
  return __builtin_bit_cast(u16, (__bf16)f);
}
__device__ __forceinline__ float b2f(u32 bits) {
  return __builtin_bit_cast(float, bits << 16);
}

// ---- workspace layout (bf16 element offsets) ----
// ROUND-14: weight regions are FRAGMENT-PACKED for 32x32x16 MFMA:
// packed[( (n>>5)*(KK/16) + (k>>4) )*512 + lane*8 + j] = M[n][k],
// n = ntile*32 + (lane&31), k = kstep*16 + (lane>>5)*8 + j.
// (A/B frag: lane holds row|col = lane&31, k = (lane>>5)*8+j — the 32x32
// analog of the 16x16 pattern verified in rounds 0-12.)
#define OFF_Wz0b 0          /* [N=512][K=64]  fwd L0 */
#define OFF_Wx0b 32768
#define OFF_Wx1b 65536
#define OFF_Wx2b 98304
#define OFF_Wz1b 131072     /* [N=512][K=512] fwd */
#define OFF_Wz2b 393216
#define OFF_Wz3b 655360
#define OFF_Wz1t 917504     /* [N=512][K=512] transposed, bwd */
#define OFF_Wz2t 1179648
#define OFF_Wz3t 1441792
#define OFF_Wz0t 1703936    /* [N=64][K=512] transposed grad weights */
#define OFF_Wx0t 1736704
#define OFF_Wx1t 1769472
#define OFF_Wx2t 1802240
#define OFF_WEND 1835008
#define WS_ELEMS OFF_WEND   /* workspace is weights only (no slabs since R9) */

// ---- weight prep: fp32 -> bf16, fragment-packed for 32x32x16 ----
__global__ __launch_bounds__(256) void prep_kernel(
    const float* __restrict__ Wz0, const float* __restrict__ Wz1,
    const float* __restrict__ Wz2, const float* __restrict__ Wz3,
    const float* __restrict__ Wx0, const float* __restrict__ Wx1,
    const float* __restrict__ Wx2, u16* __restrict__ wsb) {
  int i = blockIdx.x * 256 + threadIdx.x;   // grid exactly covers OFF_WEND
  const float* src;
  int NN, KK, trans, p;
  if (i < 131072) {                          // x-path fwd: [512][64] direct
    int r = i >> 15; p = i & 32767;
    src = (r == 0) ? Wz0 : (r == 1) ? Wx0 : (r == 2) ? Wx1 : Wx2;
    NN = 512; KK = 64; trans = 0;
  } else if (i < 917504) {                   // H fwd: [512][512] direct
    int j = i - 131072; int r = j >> 18; p = j & 262143;
    src = (r == 0) ? Wz1 : (r == 1) ? Wz2 : Wz3;
    NN = 512; KK = 512; trans = 0;
  } else if (i < 1703936) {                  // H bwd: transposed
    int j = i - 917504; int r = j >> 18; p = j & 262143;
    src = (r == 0) ? Wz1 : (r == 1) ? Wz2 : Wz3;
    NN = 512; KK = 512; trans = 1;
  } else {                                   // grad weights: [64][512] = W^T
    int j = i - 1703936; int r = j >> 15; p = j & 32767;
    src = (r == 0) ? Wz0 : (r == 1) ? Wx0 : (r == 2) ? Wx1 : Wx2;
    NN = 64; KK = 512; trans = 1;
  }
  int jj = p & 7, lane = (p >> 3) & 63, blk = p >> 9;
  int kt_sh = (KK == 64) ? 2 : 5;            // log2(KK/16)
  int ntile = blk >> kt_sh;
  int kstep = blk & ((1 << kt_sh) - 1);
  int n = ntile * 32 + (lane & 31);
  int k = kstep * 16 + ((lane >> 5) << 3) + jj;
  float v = trans ? src[k * NN + n] : src[n * KK + k];
  wsb[i] = (u16)f2b(v);
}

__global__ __launch_bounds__(256) void fill_sentinel(float* out, int n) {
  int i = blockIdx.x * 256 + threadIdx.x;
  if (i < n) out[i] = 12345.0f;   // unmistakable "workspace too small" marker
}

// ---- fully-fused ICNN fwd+bwd (single GEMM kernel) ----
// ROUND-14 = ROUND-12 (346us; MFMA-pipe 110us, VALU 152us, stall 83us;
// R13 proved BM must stay 64: fwdH already rides the aggregate L2 BW
// ceiling) with all matmuls moved to mfma_f32_32x32x16_bf16:
//  - matrix-pipe rate 844 -> 969 FLOP/cy/SIMD (floor 110 -> ~101us);
//  - MFMA instruction count HALVED (issue-slot + bookkeeping pressure);
//  - B-prefetch live set halved (1 frag/step).
// Layouts (derived from guide-verified m74/m101): C/D col=lane&31,
// row=(reg&3)+8*(reg>>2)+4*(lane>>5); A/B k=(lane>>5)*8+j.
// zbuf: K-major 1KB chunks per (kstep16, rowtile32), stride CH=520 u16
// (pad de-conflicts epi scatter writes; reads stay contiguous bursts).
// Epi simplification: per-lane col is CONSTANT -> 1 bias/WzL load/wave.
// minigrad: 32x32, 4 tiles x 4 K-quarters across 16 waves, final LDS-park
// (in dead zbB) + 4-way reduce.
// Carried: B global->VGPR depth-2 rotation, register sigmoids, ping-pong
// zbuf, 8 LDS-only barriers, setprio, col-split (wave w: cols [w*32,+32)).
// LDS = 2x65KB zbuf + 9.2KB xbuf = 139.3KB, 1 block/CU, 16 waves.
__global__ __launch_bounds__(1024, 4) void icnn_kernel(
    const float* __restrict__ state,
    const float* __restrict__ bz0, const float* __restrict__ bx0,
    const float* __restrict__ bx1, const float* __restrict__ bx2,
    const float* __restrict__ WzL, const float* __restrict__ WxL,
    u16* __restrict__ wsw, float* __restrict__ out) {
  __shared__ u16 zbA[64 * CH];      // 32 ksteps x 2 rowtiles, ping (65 KB)
  __shared__ u16 zbB[64 * CH];      // pong (65 KB); park reuses this at end
  __shared__ u16 xbuf[BM * 72];     // padded x staging, 9.2 KB

  const int tid = threadIdx.x;
  const int w = tid >> 6;           // 0..15
  const int lane = tid & 63;
  const int l31 = lane & 31;
  const int q5 = lane >> 5;
  const int blk = blockIdx.x;

  const u16* Wz0b = wsw + OFF_Wz0b;
  const u16* Wx0b = wsw + OFF_Wx0b;
  const u16* Wx1b = wsw + OFF_Wx1b;
  const u16* Wx2b = wsw + OFF_Wx2b;
  const u16* Wz1b = wsw + OFF_Wz1b;
  const u16* Wz2b = wsw + OFF_Wz2b;
  const u16* Wz3b = wsw + OFF_Wz3b;
  const u16* Wz1t = wsw + OFF_Wz1t;
  const u16* Wz2t = wsw + OFF_Wz2t;
  const u16* Wz3t = wsw + OFF_Wz3t;
  const u16* Wz0t = wsw + OFF_Wz0t;
  const u16* Wx0t = wsw + OFF_Wx0t;
  const u16* Wx1t = wsw + OFF_Wx1t;
  const u16* Wx2t = wsw + OFF_Wx2t;

  auto lbar = [&]() {               // LDS-only barrier (no vmcnt drain)
    asm volatile("s_waitcnt lgkmcnt(0)" ::: "memory");
    __builtin_amdgcn_s_barrier();
    asm volatile("" ::: "memory");
  };

  // ---- stage x = state-1 into xbuf (bf16, padded row-major) ----
  {
    int r = tid >> 4, c0 = (tid & 15) << 2;  // 64 rows x 16 chunks of 4 floats
    const float* p = state + (blk * BM + r) * D + c0;
    f32x4 v = __builtin_nontemporal_load((const f32x4*)p);
    u32* dst = (u32*)&xbuf[r * 72 + c0];
    dst[0] = (u32)f2bc(v[0] - 1.0f) | ((u32)f2bc(v[1] - 1.0f) << 16);
    dst[1] = (u32)f2bc(v[2] - 1.0f) | ((u32)f2bc(v[3] - 1.0f) << 16);
  }

  const f32x16 Z16 = {0,0,0,0,0,0,0,0,0,0,0,0,0,0,0,0};
  f32x16 acc[2];                    // 2 rowtiles x 16 C-regs = 32 acc regs
  f32x16 pk = Z16;                  // grad partial: tile (w&1,(w>>1)&1), kq=w>>2
  u64 sg0[8], sg1[8], sg2[8];       // register-resident sigmoids

  // z[row][k] lives at chunk(ks=k>>4, rt=row>>5), elem
  // ((row&31)|(((k>>3)&1)<<5))*8 + (k&7). A-frag read (rt, ks) = one
  // contiguous 1KB burst at (ks*2+rt)*CH + lane*8.
  auto ldA = [&](const u16* zb, int rt, int ks) -> bf16x8 {
    return *(const bf16x8*)(&zb[(ks * 2 + rt) * CH + lane * 8]);
  };
  auto ldX = [&](int rt, int ks) -> bf16x8 {   // x A-frag from padded xbuf
    return *(const bf16x8*)(&xbuf[(rt * 32 + l31) * 72 + ks * 16 + q5 * 8]);
  };

  // acc = x @ Wx^T (K=64), zero-start. Wx streams global->VGPR.
  auto fwdX = [&](const u16* Wxp) {
    const u16* xb = Wxp + (w * 4) * 512 + lane * 8;   // ntile = w, 4 ksteps
#pragma unroll
    for (int ks = 0; ks < 4; ++ks) {
      bf16x8 b = *(const bf16x8*)(xb + ks * 512);
      bf16x8 a0 = ldX(0, ks);
      bf16x8 a1 = ldX(1, ks);
      acc[0] = __builtin_amdgcn_mfma_f32_32x32x16_bf16(a0, b, (ks == 0) ? Z16 : acc[0], 0, 0, 0);
      acc[1] = __builtin_amdgcn_mfma_f32_32x32x16_bf16(a1, b, (ks == 0) ? Z16 : acc[1], 0, 0, 0);
    }
  };

  // acc += zb @ W^T (K=512), ALWAYS accumulating. B streams global->VGPR,
  // depth-2 rotation (3 live frags = 12 regs); 32 ksteps of 16.
  auto fwdH = [&](const u16* Wp, const u16* zb) {
    const u16* gb = Wp + (w * 32) * 512 + lane * 8;   // ntile = w
    bf16x8 b0 = *(const bf16x8*)(gb);
    bf16x8 b1 = *(const bf16x8*)(gb + 512);
#pragma unroll 2
    for (int st = 0; st < 32; ++st) {
      int stp = (st < 30) ? st + 2 : st;   // prefetch st+2 (clamped re-read)
      bf16x8 bn = *(const bf16x8*)(gb + stp * 512);
      bf16x8 a0 = ldA(zb, 0, st);
      bf16x8 a1 = ldA(zb, 1, st);
      __builtin_amdgcn_s_setprio(1);
      acc[0] = __builtin_amdgcn_mfma_f32_32x32x16_bf16(a0, b0, acc[0], 0, 0, 0);
      acc[1] = __builtin_amdgcn_mfma_f32_32x32x16_bf16(a1, b0, acc[1], 0, 0, 0);
      __builtin_amdgcn_s_setprio(0);
      b0 = b1; b1 = bn;
    }
  };
  auto zeroAcc = [&]() { acc[0] = Z16; acc[1] = Z16; };

  // Per-lane constant write base for epi scatter into zbuf:
  // col n = w*32 + l31 (fixed per lane); row = rt*32 + e + 8g + 4*q5.
  const int C0 = (2 * w + (l31 >> 4)) * (2 * CH) + ((l31 >> 3) & 1) * 256 + (l31 & 7);

  // forward epilogue: a+=bias; z=softplus -> zb; s=sigmoid -> sg (registers)
  auto fwd_epi = [&](const float* biasp, u64 (&sg)[8], u16* zb) {
    float bias = biasp[w * 32 + l31];
#pragma unroll
    for (int rt = 0; rt < 2; ++rt)
#pragma unroll
      for (int g = 0; g < 4; ++g) {
        u64 pack = 0;
#pragma unroll
        for (int e = 0; e < 4; ++e) {
          float a = acc[rt][g * 4 + e] + bias;
          float t = __expf(-a);
          float u = 1.0f + t;
          float s = __builtin_amdgcn_rcpf(u);     // sigmoid(a)
          float z = a + __logf(u);                // softplus(a)
          pack |= (u64)f2bc(s) << (16 * e);
          zb[C0 + rt * CH + (e + 8 * g + 4 * q5) * 8] = f2bc(z);
        }
        sg[rt * 4 + g] = pack;
      }
  };
  auto d3_epi = [&](const float* biasp, u16* zb) {  // d3 = WzL*sigmoid(a3)
    float bias = biasp[w * 32 + l31];
    float wl = WzL[w * 32 + l31];
#pragma unroll
    for (int rt = 0; rt < 2; ++rt)
#pragma unroll
      for (int g = 0; g < 4; ++g)
#pragma unroll
        for (int e = 0; e < 4; ++e) {
          float a = acc[rt][g * 4 + e] + bias;
          float t = __expf(-a);
          float s = __builtin_amdgcn_rcpf(1.0f + t);
          zb[C0 + rt * CH + (e + 8 * g + 4 * q5) * 8] = f2bc(wl * s);
        }
  };
  // d = g * s -> zb (s from registers; same thread produced both)
  auto bwd_epi = [&](const u64 (&sg)[8], u16* zb) {
#pragma unroll
    for (int rt = 0; rt < 2; ++rt)
#pragma unroll
      for (int g = 0; g < 4; ++g) {
        u64 v = sg[rt * 4 + g];
#pragma unroll
        for (int e = 0; e < 4; ++e) {
          float s = b2f((u32)(v >> (16 * e)) & 0xffffu);
          float d = acc[rt][g * 4 + e] * s;
          zb[C0 + rt * CH + (e + 8 * g + 4 * q5) * 8] = f2bc(d);
        }
      }
  };

  // grad mini-phase: pk += zb(d)-tile @ Wg-tile over this wave's K-quarter.
  // 16 waves = 4 tiles (tr=w&1, tc=(w>>1)&1) x 4 K-quarters (kq=w>>2).
  auto minigrad = [&](const u16* Wg, const u16* zb, bool init) {
    int tr = w & 1, tc = (w >> 1) & 1, kq = w >> 2;
    const u16* gb = Wg + (tc * 32 + kq * 8) * 512 + lane * 8;
    f32x16 t = pk;
    if (init) t = Z16;
#pragma unroll 2
    for (int i = 0; i < 8; ++i) {
      bf16x8 a = ldA(zb, tr, kq * 8 + i);
      bf16x8 g = *(const bf16x8*)(gb + i * 512);
      __builtin_amdgcn_s_setprio(1);
      t = __builtin_amdgcn_mfma_f32_32x32x16_bf16(a, g, t, 0, 0, 0);
      __builtin_amdgcn_s_setprio(0);
    }
    pk = t;
  };

  // ---------------- forward ----------------
  lbar();                                   // xbuf ready
  fwdX(Wz0b);                               // a0 = x@Wz0^T
  fwd_epi(bz0, sg0, zbA);                   // z0 -> zbA, s0 -> regs
  lbar();                                   // P0
  fwdX(Wx0b); fwdH(Wz1b, zbA);              // a1 = x@Wx0^T + z0@Wz1^T
  fwd_epi(bx0, sg1, zbB);                   // z1 -> zbB (zbA still readable)
  lbar();                                   // P1
  fwdX(Wx1b); fwdH(Wz2b, zbB);              // a2
  fwd_epi(bx1, sg2, zbA);                   // z2 -> zbA
  lbar();                                   // P2
  fwdX(Wx2b); fwdH(Wz3b, zbA);              // a3
  d3_epi(bx2, zbB);                         // d3 -> zbB
  lbar();                                   // P3
  // ---------------- backward ----------------
  minigrad(Wx2t, zbB, true);                // pk  = d3@Wx2t (this wave's slice)
  zeroAcc(); fwdH(Wz3t, zbB);               // acc = d3@Wz3
  bwd_epi(sg2, zbA);                        // d2 -> zbA
  lbar();                                   // P4
  minigrad(Wx1t, zbA, false);               // pk += d2@Wx1t
  zeroAcc(); fwdH(Wz2t, zbA);               // acc = d2@Wz2
  bwd_epi(sg1, zbB);                        // d1 -> zbB
  lbar();                                   // P5
  minigrad(Wx0t, zbB, false);               // pk += d1@Wx0t
  zeroAcc(); fwdH(Wz1t, zbB);               // acc = d1@Wz1
  bwd_epi(sg0, zbA);                        // d0 -> zbA
  lbar();                                   // P6 (zbB dead after this point)
  // ---- final: out = d0@Wz0t + pk + WxL, 4-way K-reduce via park in zbB ----
  minigrad(Wz0t, zbA, false);               // pk += d0@Wz0t
  {
    float* park = (float*)zbB;              // 16 waves x 16 regs x 64 lanes f32
#pragma unroll
    for (int reg = 0; reg < 16; ++reg)
      park[(w * 16 + reg) * 64 + lane] = pk[reg];
  }
  lbar();
  {
    int t = w & 3, rg = w >> 2;             // tile t, reg-group rg
    int tr = t & 1, tc = (t >> 1) & 1;
    int col = tc * 32 + l31;
    float wx = WxL[col];
    const float* park = (const float*)zbB;
#pragma unroll
    for (int e = 0; e < 4; ++e) {
      int reg = rg * 4 + e;
      float v = park[(t * 16 + reg) * 64 + lane]
              + park[((t + 4) * 16 + reg) * 64 + lane]
              + park[((t + 8) * 16 + reg) * 64 + lane]
              + park[((t + 12) * 16 + reg) * 64 + lane];
      int row = blk * BM + tr * 32 + e + 8 * rg + 4 * q5;
      out[row * D + col] = v + wx;
    }
  }
}

extern "C" void kernel_launch(void* const* d_in, const int* in_sizes, int n_in,
                              void* d_out, int out_size, void* d_ws, size_t ws_size,
                              hipStream_t stream) {
  const float* state = (const float*)d_in[0];
  const float* Wz0 = (const float*)d_in[1];
  const float* bz0 = (const float*)d_in[2];
  const float* Wz1 = (const float*)d_in[3];
  const float* Wz2 = (const float*)d_in[4];
  const float* Wz3 = (const float*)d_in[5];
  const float* WzL = (const float*)d_in[6];
  const float* Wx0 = (const float*)d_in[7];
  const float* bx0 = (const float*)d_in[8];
  const float* Wx1 = (const float*)d_in[9];
  const float* bx1 = (const float*)d_in[10];
  const float* Wx2 = (const float*)d_in[11];
  const float* bx2 = (const float*)d_in[12];
  const float* WxL = (const float*)d_in[13];

  if (ws_size < (size_t)WS_ELEMS * 2) {
    fill_sentinel<<<(out_size + 255) / 256, 256, 0, stream>>>((float*)d_out, out_size);
    return;
  }
  u16* wsw = (u16*)d_ws;
  prep_kernel<<<OFF_WEND / 256, 256, 0, stream>>>(Wz0, Wz1, Wz2, Wz3, Wx0, Wx1, Wx2, wsw);
  icnn_kernel<<<B_TOTAL / BM, 1024, 0, stream>>>(state, bz0, bx0, bx1, bx2, WzL, WxL,
                                                 wsw, (float*)d_out);
}